// Round 1
// baseline (464.107 us; speedup 1.0000x reference)
//
#include <hip/hip_runtime.h>
#include <stdint.h>

// Problem constants (B,N,D,H fixed by setup_inputs)
#define B_  8
#define N_  768
#define D_  2048
#define H_  4
#define HN  192   // head width n = N/H

typedef unsigned short u16;
typedef float    f32x4 __attribute__((ext_vector_type(4)));
typedef __bf16   bf16x8 __attribute__((ext_vector_type(8)));
typedef uint32_t u32x4 __attribute__((ext_vector_type(4)));
typedef uint32_t u32x2 __attribute__((ext_vector_type(2)));

__device__ __forceinline__ u16 f2bf(float f) {
  uint32_t u = __builtin_bit_cast(uint32_t, f);
  u += 0x7fffu + ((u >> 16) & 1u);   // round-to-nearest-even
  return (u16)(u >> 16);
}

// ---------------------------------------------------------------------------
// Kernel 0: transpose x (B,N,D) fp32 -> xt (B,D,N) bf16
// ---------------------------------------------------------------------------
__global__ __launch_bounds__(256) void transpose_x(const float* __restrict__ x,
                                                   u16* __restrict__ xt) {
  __shared__ float tile[64][65];
  const int d0 = blockIdx.x * 64;
  const int n0 = blockIdx.y * 64;
  const int b  = blockIdx.z;
  const int t   = threadIdx.x;
  const int col = t & 63;
  const int rb  = (t >> 6) * 16;
  const float* src = x + ((size_t)b * N_ + n0) * D_ + d0;
  #pragma unroll
  for (int i = 0; i < 16; i++)
    tile[rb + i][col] = src[(size_t)(rb + i) * D_ + col];
  __syncthreads();
  u16* dst = xt + ((size_t)b * D_ + d0) * N_ + n0;
  #pragma unroll
  for (int i = 0; i < 16; i++)
    dst[(size_t)(rb + i) * N_ + col] = f2bf(tile[col][rb + i]);
}

// ---------------------------------------------------------------------------
// Kernel 0b: convert the three weight matrices fp32 -> bf16
// ---------------------------------------------------------------------------
__global__ __launch_bounds__(256) void cvt_w(const float* __restrict__ a,
                                             const float* __restrict__ b,
                                             const float* __restrict__ c,
                                             u16* __restrict__ oa,
                                             u16* __restrict__ ob,
                                             u16* __restrict__ oc) {
  const float* src = (blockIdx.y == 0) ? a : ((blockIdx.y == 1) ? b : c);
  u16*         dst = (blockIdx.y == 0) ? oa : ((blockIdx.y == 1) ? ob : oc);
  const int i = (blockIdx.x * 256 + threadIdx.x) * 4;
  f32x4 v = *(const f32x4*)(src + i);
  u16 tmp[4];
  #pragma unroll
  for (int j = 0; j < 4; j++) tmp[j] = f2bf(v[j]);
  *(u32x2*)(dst + i) = *(u32x2*)tmp;
}

// ---------------------------------------------------------------------------
// Kernel 0c: zero the q2 accumulator (ws is poisoned 0xAA each launch)
// ---------------------------------------------------------------------------
__global__ __launch_bounds__(256) void zero_q2(float* __restrict__ q2) {
  q2[blockIdx.x * 256 + threadIdx.x] = 0.f;
}

// ---------------------------------------------------------------------------
// Kernel 1: fused QK/V GEMM.
//   qk[bh,d,jn] = sum_k xt[b,d,k] * Wqk[j,k]      (bf16 out)
//   vt[bh,jn,e=d] = sum_k xt[b,d,k] * Wv[j,k]     (bf16, transposed layout)
//   q2[bh,d]   += sum_jn qk^2                      (fp32 atomics)
// Block: 64(d) x 64(j) tile, BK=32, 4 waves (2x2), 16x16x32 bf16 MFMA.
// ---------------------------------------------------------------------------
__global__ __launch_bounds__(256) void qkv_gemm(const u16* __restrict__ xt,
                                                const u16* __restrict__ wqk,
                                                const u16* __restrict__ wv,
                                                u16* __restrict__ qkb,
                                                u16* __restrict__ vtb,
                                                float* __restrict__ q2) {
  const int b  = blockIdx.z;
  const int d0 = blockIdx.x * 64;
  const int j0 = blockIdx.y * 64;
  const int h   = j0 / HN;          // 64-tile never straddles a head (192=3*64)
  const int jn0 = j0 - h * HN;
  const int tid  = threadIdx.x;
  const int wave = tid >> 6, lane = tid & 63;
  const int l15  = lane & 15, quad = lane >> 4;
  const int wm = wave >> 1, wn = wave & 1;

  __shared__ u16 At[64][40];   // +8 pad: b128 start-bank stride 20 mod 32
  __shared__ u16 Bq[64][40];
  __shared__ u16 Bv[64][40];
  __shared__ float vtile[64][68];

  const f32x4 fz = {0.f, 0.f, 0.f, 0.f};
  f32x4 accq[2][2], accv[2][2];
  #pragma unroll
  for (int i = 0; i < 2; i++)
    #pragma unroll
    for (int j = 0; j < 2; j++) { accq[i][j] = fz; accv[i][j] = fz; }

  const int srow = tid >> 2;
  const int soff = (tid & 3) * 8;
  const u16* ax = xt  + ((size_t)b * D_ + d0 + srow) * N_ + soff;
  const u16* bq = wqk + (size_t)(j0 + srow) * N_ + soff;
  const u16* bv = wv  + (size_t)(j0 + srow) * N_ + soff;

  for (int k0 = 0; k0 < N_; k0 += 32) {
    __syncthreads();
    *(u32x4*)&At[srow][soff] = *(const u32x4*)(ax + k0);
    *(u32x4*)&Bq[srow][soff] = *(const u32x4*)(bq + k0);
    *(u32x4*)&Bv[srow][soff] = *(const u32x4*)(bv + k0);
    __syncthreads();
    bf16x8 Af[2], Bqf[2], Bvf[2];
    #pragma unroll
    for (int mi = 0; mi < 2; mi++)
      Af[mi] = *(const bf16x8*)&At[wm * 32 + mi * 16 + l15][quad * 8];
    #pragma unroll
    for (int ni = 0; ni < 2; ni++) {
      Bqf[ni] = *(const bf16x8*)&Bq[wn * 32 + ni * 16 + l15][quad * 8];
      Bvf[ni] = *(const bf16x8*)&Bv[wn * 32 + ni * 16 + l15][quad * 8];
    }
    #pragma unroll
    for (int mi = 0; mi < 2; mi++)
      #pragma unroll
      for (int ni = 0; ni < 2; ni++) {
        accq[mi][ni] = __builtin_amdgcn_mfma_f32_16x16x32_bf16(Af[mi], Bqf[ni], accq[mi][ni], 0, 0, 0);
        accv[mi][ni] = __builtin_amdgcn_mfma_f32_16x16x32_bf16(Af[mi], Bvf[ni], accv[mi][ni], 0, 0, 0);
      }
  }

  // epilogue: qk store (C layout: col=lane&15, row=quad*4+r) + q2 atomics
  const size_t bh = (size_t)(b * H_ + h);
  u16* qbase = qkb + bh * (size_t)D_ * HN;
  #pragma unroll
  for (int mi = 0; mi < 2; mi++)
    #pragma unroll
    for (int r = 0; r < 4; r++) {
      const int d = d0 + wm * 32 + mi * 16 + quad * 4 + r;
      float ssq = 0.f;
      #pragma unroll
      for (int ni = 0; ni < 2; ni++) {
        float val = accq[mi][ni][r];
        ssq += val * val;
        qbase[(size_t)d * HN + jn0 + wn * 32 + ni * 16 + l15] = f2bf(val);
      }
      ssq += __shfl_xor(ssq, 1, 64);
      ssq += __shfl_xor(ssq, 2, 64);
      ssq += __shfl_xor(ssq, 4, 64);
      ssq += __shfl_xor(ssq, 8, 64);
      if (l15 == 0) atomicAdd(&q2[bh * D_ + d], ssq);
    }

  // epilogue: v -> LDS transpose -> coalesced bf16 store in (bh, jn, e) layout
  #pragma unroll
  for (int mi = 0; mi < 2; mi++)
    #pragma unroll
    for (int ni = 0; ni < 2; ni++)
      #pragma unroll
      for (int r = 0; r < 4; r++)
        vtile[wn * 32 + ni * 16 + l15][wm * 32 + mi * 16 + quad * 4 + r] = accv[mi][ni][r];
  __syncthreads();
  const int jl = tid >> 2;
  const int ch = (tid & 3) * 16;
  u16 tmp[16];
  #pragma unroll
  for (int i = 0; i < 16; i++) tmp[i] = f2bf(vtile[jl][ch + i]);
  u16* vdst = vtb + (bh * HN + jn0 + jl) * (size_t)D_ + d0 + ch;
  *(u32x4*)(vdst)     = *(u32x4*)&tmp[0];
  *(u32x4*)(vdst + 8) = *(u32x4*)&tmp[8];
}

// ---------------------------------------------------------------------------
// Kernel 2: fused flash attention over channels.
//   logits(d,e) = 2*Q.K - q2[e]   (row term -q2[d] cancels in softmax)
//   O = softmax_e(logits) @ V ; written merged-head to w (B,D,N) bf16.
// Block: one (b,h), 64 Q-rows; wave handles 16 rows x full n=192.
// ---------------------------------------------------------------------------
__global__ __launch_bounds__(256) void attn_kernel(const u16* __restrict__ qkb,
                                                   const u16* __restrict__ vtb,
                                                   const float* __restrict__ q2,
                                                   u16* __restrict__ wbuf) {
  const int bh = blockIdx.y;
  const int b = bh >> 2, h = bh & 3;
  const int d0 = blockIdx.x * 64;
  const int tid  = threadIdx.x;
  const int wave = tid >> 6, lane = tid & 63;
  const int l15  = lane & 15, quad = lane >> 4;

  __shared__ u16 Kt[64][200];     // 192 + 8 pad
  __shared__ u16 Vt[HN][72];      // V^T tile: [jn][e], 64 + 8 pad
  __shared__ u16 Pl[4][16][72];   // per-wave P round-trip (C->A layout)
  __shared__ float q2t[64];

  // Q fragments (A layout: m=lane&15, k=quad*8+j), rows d0+wave*16+[0,16)
  bf16x8 Qf[6];
  {
    const u16* qsrc = qkb + ((size_t)bh * D_ + d0 + wave * 16 + l15) * HN + quad * 8;
    #pragma unroll
    for (int f = 0; f < 6; f++) Qf[f] = *(const bf16x8*)(qsrc + f * 32);
  }

  const f32x4 fz = {0.f, 0.f, 0.f, 0.f};
  f32x4 O[12];
  #pragma unroll
  for (int c = 0; c < 12; c++) O[c] = fz;
  float mst[4], lst[4];
  #pragma unroll
  for (int r = 0; r < 4; r++) { mst[r] = -1e30f; lst[r] = 0.f; }

  const u16* ksrc = qkb + (size_t)bh * D_ * HN;
  const u16* vsrc = vtb + (size_t)bh * HN * D_;
  const float* q2src = q2 + (size_t)bh * D_;

  for (int e0 = 0; e0 < D_; e0 += 64) {
    __syncthreads();
    // stage K tile (64 x 192, contiguous in global)
    #pragma unroll
    for (int it = 0; it < 6; it++) {
      int c = tid + it * 256;           // 1536 chunks of 16B
      int row = c / 24, off = (c % 24) * 8;
      *(u32x4*)&Kt[row][off] = *(const u32x4*)(ksrc + (size_t)(e0 + row) * HN + off);
    }
    // stage V^T tile (192 rows x 64)
    #pragma unroll
    for (int it = 0; it < 6; it++) {
      int c = tid + it * 256;
      int j = c >> 3, off = (c & 7) * 8;
      *(u32x4*)&Vt[j][off] = *(const u32x4*)(vsrc + (size_t)j * D_ + e0 + off);
    }
    if (tid < 64) q2t[tid] = q2src[e0 + tid];
    __syncthreads();

    // S = Q K^T (16 rows x 64 cols per wave)
    f32x4 S[4];
    #pragma unroll
    for (int ni = 0; ni < 4; ni++) {
      f32x4 acc = fz;
      #pragma unroll
      for (int f = 0; f < 6; f++) {
        bf16x8 Kf = *(const bf16x8*)&Kt[ni * 16 + l15][f * 32 + quad * 8];
        acc = __builtin_amdgcn_mfma_f32_16x16x32_bf16(Qf[f], Kf, acc, 0, 0, 0);
      }
      S[ni] = acc;
    }

    // logits = 2*S - q2[e]; online softmax (rows = quad*4+r, cols = lane&15)
    float rowmax[4] = {-1e30f, -1e30f, -1e30f, -1e30f};
    #pragma unroll
    for (int ni = 0; ni < 4; ni++) {
      float qe = q2t[ni * 16 + l15];
      #pragma unroll
      for (int r = 0; r < 4; r++) {
        float v = 2.f * S[ni][r] - qe;
        S[ni][r] = v;
        rowmax[r] = fmaxf(rowmax[r], v);
      }
    }
    #pragma unroll
    for (int r = 0; r < 4; r++) {
      float m = rowmax[r];
      m = fmaxf(m, __shfl_xor(m, 1, 64));
      m = fmaxf(m, __shfl_xor(m, 2, 64));
      m = fmaxf(m, __shfl_xor(m, 4, 64));
      m = fmaxf(m, __shfl_xor(m, 8, 64));
      rowmax[r] = m;
    }
    float alpha[4], rowsum[4];
    #pragma unroll
    for (int r = 0; r < 4; r++) {
      float mnew = fmaxf(mst[r], rowmax[r]);
      alpha[r] = __expf(mst[r] - mnew);
      mst[r] = mnew;
      rowsum[r] = 0.f;
    }
    #pragma unroll
    for (int ni = 0; ni < 4; ni++)
      #pragma unroll
      for (int r = 0; r < 4; r++) {
        float p = __expf(S[ni][r] - mst[r]);
        S[ni][r] = p;
        rowsum[r] += p;
      }
    #pragma unroll
    for (int r = 0; r < 4; r++) {
      float s = rowsum[r];
      s += __shfl_xor(s, 1, 64);
      s += __shfl_xor(s, 2, 64);
      s += __shfl_xor(s, 4, 64);
      s += __shfl_xor(s, 8, 64);
      lst[r] = lst[r] * alpha[r] + s;
    }
    #pragma unroll
    for (int c = 0; c < 12; c++)
      #pragma unroll
      for (int r = 0; r < 4; r++)
        O[c][r] *= alpha[r];
    // P: C layout -> LDS -> A layout
    #pragma unroll
    for (int ni = 0; ni < 4; ni++)
      #pragma unroll
      for (int r = 0; r < 4; r++)
        Pl[wave][quad * 4 + r][ni * 16 + l15] = f2bf(S[ni][r]);
    __syncthreads();
    #pragma unroll
    for (int kk = 0; kk < 2; kk++) {
      bf16x8 Pf = *(const bf16x8*)&Pl[wave][l15][kk * 32 + quad * 8];
      #pragma unroll
      for (int c = 0; c < 12; c++) {
        bf16x8 Vf = *(const bf16x8*)&Vt[c * 16 + l15][kk * 32 + quad * 8];
        O[c] = __builtin_amdgcn_mfma_f32_16x16x32_bf16(Pf, Vf, O[c], 0, 0, 0);
      }
    }
  }

  // normalize + merged-head store: w[b, d, h*192 + col] bf16
  #pragma unroll
  for (int r = 0; r < 4; r++) {
    const float inv = 1.f / lst[r];
    const int d = d0 + wave * 16 + quad * 4 + r;
    u16* wrow = wbuf + ((size_t)b * D_ + d) * N_ + h * HN;
    #pragma unroll
    for (int c = 0; c < 12; c++)
      wrow[c * 16 + l15] = f2bf(O[c][r] * inv);
  }
}

// ---------------------------------------------------------------------------
// Kernel 3: out GEMM + transpose.  out[b,i,d] = sum_j w[b,d,j]*Wout[i,j] (fp32)
// ---------------------------------------------------------------------------
__global__ __launch_bounds__(256) void out_gemm(const u16* __restrict__ wbuf,
                                                const u16* __restrict__ wout,
                                                float* __restrict__ outp) {
  const int b  = blockIdx.z;
  const int d0 = blockIdx.x * 64;
  const int i0 = blockIdx.y * 64;
  const int tid  = threadIdx.x;
  const int wave = tid >> 6, lane = tid & 63;
  const int l15  = lane & 15, quad = lane >> 4;
  const int wm = wave >> 1, wn = wave & 1;

  __shared__ u16 At[64][40];
  __shared__ u16 Bt[64][40];
  __shared__ float otile[64][68];

  const f32x4 fz = {0.f, 0.f, 0.f, 0.f};
  f32x4 acc[2][2];
  #pragma unroll
  for (int i = 0; i < 2; i++)
    #pragma unroll
    for (int j = 0; j < 2; j++) acc[i][j] = fz;

  const int srow = tid >> 2;
  const int soff = (tid & 3) * 8;
  const u16* ax = wbuf + ((size_t)b * D_ + d0 + srow) * N_ + soff;
  const u16* bw = wout + (size_t)(i0 + srow) * N_ + soff;

  for (int k0 = 0; k0 < N_; k0 += 32) {
    __syncthreads();
    *(u32x4*)&At[srow][soff] = *(const u32x4*)(ax + k0);
    *(u32x4*)&Bt[srow][soff] = *(const u32x4*)(bw + k0);
    __syncthreads();
    bf16x8 Af[2], Bf[2];
    #pragma unroll
    for (int mi = 0; mi < 2; mi++)
      Af[mi] = *(const bf16x8*)&At[wm * 32 + mi * 16 + l15][quad * 8];
    #pragma unroll
    for (int ni = 0; ni < 2; ni++)
      Bf[ni] = *(const bf16x8*)&Bt[wn * 32 + ni * 16 + l15][quad * 8];
    #pragma unroll
    for (int mi = 0; mi < 2; mi++)
      #pragma unroll
      for (int ni = 0; ni < 2; ni++)
        acc[mi][ni] = __builtin_amdgcn_mfma_f32_16x16x32_bf16(Af[mi], Bf[ni], acc[mi][ni], 0, 0, 0);
  }

  #pragma unroll
  for (int mi = 0; mi < 2; mi++)
    #pragma unroll
    for (int ni = 0; ni < 2; ni++)
      #pragma unroll
      for (int r = 0; r < 4; r++)
        otile[wn * 32 + ni * 16 + l15][wm * 32 + mi * 16 + quad * 4 + r] = acc[mi][ni][r];
  __syncthreads();
  const int il = tid >> 2;
  const int ch = (tid & 3) * 16;
  float* orow = outp + ((size_t)b * N_ + i0 + il) * D_ + d0 + ch;
  #pragma unroll
  for (int i = 0; i < 16; i += 4)
    *(f32x4*)(orow + i) = *(const f32x4*)&otile[il][ch + i];
}

// ---------------------------------------------------------------------------
extern "C" void kernel_launch(void* const* d_in, const int* in_sizes, int n_in,
                              void* d_out, int out_size, void* d_ws, size_t ws_size,
                              hipStream_t stream) {
  (void)in_sizes; (void)n_in; (void)out_size; (void)ws_size;
  const float* x    = (const float*)d_in[0];
  const float* Wqk  = (const float*)d_in[1];
  const float* Wv   = (const float*)d_in[2];
  const float* Wout = (const float*)d_in[3];
  float* outp = (float*)d_out;

  // Workspace layout (~79 MB total; all offsets 256B-aligned)
  char* ws = (char*)d_ws;
  size_t off = 0;
  u16* xt   = (u16*)(ws + off); off += (size_t)B_ * D_ * N_ * 2;        // 25.2 MB
  u16* qkb  = (u16*)(ws + off); off += (size_t)B_ * H_ * D_ * HN * 2;   // 25.2 MB
  u16* vtb  = (u16*)(ws + off); off += (size_t)B_ * H_ * HN * D_ * 2;   // 25.2 MB
  float* q2 = (float*)(ws + off); off += (size_t)B_ * H_ * D_ * 4;      // 256 KB
  u16* wqk_bf  = (u16*)(ws + off); off += (size_t)N_ * N_ * 2;
  u16* wv_bf   = (u16*)(ws + off); off += (size_t)N_ * N_ * 2;
  u16* wout_bf = (u16*)(ws + off); off += (size_t)N_ * N_ * 2;
  u16* wbuf = xt;   // xt dead after qkv_gemm; reuse for attention output

  transpose_x<<<dim3(D_ / 64, N_ / 64, B_), 256, 0, stream>>>(x, xt);
  cvt_w<<<dim3((N_ * N_) / (256 * 4), 3), 256, 0, stream>>>(Wqk, Wv, Wout, wqk_bf, wv_bf, wout_bf);
  zero_q2<<<dim3((B_ * H_ * D_) / 256), 256, 0, stream>>>(q2);
  qkv_gemm<<<dim3(D_ / 64, N_ / 64, B_), 256, 0, stream>>>(xt, wqk_bf, wv_bf, qkb, vtb, q2);
  attn_kernel<<<dim3(D_ / 64, B_ * H_), 256, 0, stream>>>(qkb, vtb, q2, wbuf);
  out_gemm<<<dim3(D_ / 64, N_ / 64, B_), 256, 0, stream>>>(wbuf, wout_bf, outp);
}

// Round 2
// 370.879 us; speedup vs baseline: 1.2514x; 1.2514x over previous
//
#include <hip/hip_runtime.h>
#include <stdint.h>

// Problem constants (B,N,D,H fixed by setup_inputs)
#define B_  8
#define N_  768
#define D_  2048
#define H_  4
#define HN  192   // head width n = N/H

typedef unsigned short u16;
typedef float    f32x4 __attribute__((ext_vector_type(4)));
typedef __bf16   bf16x8 __attribute__((ext_vector_type(8)));
typedef uint32_t u32x4 __attribute__((ext_vector_type(4)));
typedef uint32_t u32x2 __attribute__((ext_vector_type(2)));

__device__ __forceinline__ u16 f2bf(float f) {
  uint32_t u = __builtin_bit_cast(uint32_t, f);
  u += 0x7fffu + ((u >> 16) & 1u);   // round-to-nearest-even
  return (u16)(u >> 16);
}

// async global->LDS DMA, 16 B per lane; LDS dest = uniform base + lane*16
typedef const __attribute__((address_space(1))) void* gas_ptr;
typedef __attribute__((address_space(3))) void* las_ptr;
__device__ __forceinline__ void gld16(const void* g, void* l) {
  __builtin_amdgcn_global_load_lds((gas_ptr)g, (las_ptr)l, 16, 0, 0);
}

// ---------------------------------------------------------------------------
// Kernel 0: transpose x (B,N,D) fp32 -> xt (B,D,N) bf16
// ---------------------------------------------------------------------------
__global__ __launch_bounds__(256) void transpose_x(const float* __restrict__ x,
                                                   u16* __restrict__ xt) {
  __shared__ float tile[64][65];
  const int d0 = blockIdx.x * 64;
  const int n0 = blockIdx.y * 64;
  const int b  = blockIdx.z;
  const int t   = threadIdx.x;
  const int col = t & 63;
  const int rb  = (t >> 6) * 16;
  const float* src = x + ((size_t)b * N_ + n0) * D_ + d0;
  #pragma unroll
  for (int i = 0; i < 16; i++)
    tile[rb + i][col] = src[(size_t)(rb + i) * D_ + col];
  __syncthreads();
  u16* dst = xt + ((size_t)b * D_ + d0) * N_ + n0;
  #pragma unroll
  for (int i = 0; i < 16; i++)
    dst[(size_t)(rb + i) * N_ + col] = f2bf(tile[col][rb + i]);
}

// ---------------------------------------------------------------------------
// Kernel 0b: convert the three weight matrices fp32 -> bf16
// ---------------------------------------------------------------------------
__global__ __launch_bounds__(256) void cvt_w(const float* __restrict__ a,
                                             const float* __restrict__ b,
                                             const float* __restrict__ c,
                                             u16* __restrict__ oa,
                                             u16* __restrict__ ob,
                                             u16* __restrict__ oc) {
  const float* src = (blockIdx.y == 0) ? a : ((blockIdx.y == 1) ? b : c);
  u16*         dst = (blockIdx.y == 0) ? oa : ((blockIdx.y == 1) ? ob : oc);
  const int i = (blockIdx.x * 256 + threadIdx.x) * 4;
  f32x4 v = *(const f32x4*)(src + i);
  u16 tmp[4];
  #pragma unroll
  for (int j = 0; j < 4; j++) tmp[j] = f2bf(v[j]);
  *(u32x2*)(dst + i) = *(u32x2*)tmp;
}

// ---------------------------------------------------------------------------
// Kernel 0c: zero the q2 accumulator (ws is poisoned 0xAA each launch)
// ---------------------------------------------------------------------------
__global__ __launch_bounds__(256) void zero_q2(float* __restrict__ q2) {
  q2[blockIdx.x * 256 + threadIdx.x] = 0.f;
}

// ---------------------------------------------------------------------------
// Kernel 1: fused QK/V GEMM, outputs in fragment-tiled layout.
//   qkb[bh][dtile][jn8 24][d_local 64][8]   (bf16)  -- serves attn Q and K
//   vtb[bh][etile][e8 8][jn 192][8]         (bf16)  -- serves attn V
//   q2[bh,d] += sum_jn qk^2                  (fp32 atomics)
// Block: 64(d) x 64(j) tile, BK=32, 4 waves (2x2), 16x16x32 bf16 MFMA.
// ---------------------------------------------------------------------------
__global__ __launch_bounds__(256) void qkv_gemm(const u16* __restrict__ xt,
                                                const u16* __restrict__ wqk,
                                                const u16* __restrict__ wv,
                                                u16* __restrict__ qkb,
                                                u16* __restrict__ vtb,
                                                float* __restrict__ q2) {
  const int b  = blockIdx.z;
  const int dtile = blockIdx.x;
  const int d0 = dtile * 64;
  const int j0 = blockIdx.y * 64;
  const int h   = j0 / HN;          // 64-tile never straddles a head (192=3*64)
  const int jn0 = j0 - h * HN;
  const int tid  = threadIdx.x;
  const int wave = tid >> 6, lane = tid & 63;
  const int l15  = lane & 15, quad = lane >> 4;
  const int wm = wave >> 1, wn = wave & 1;

  __shared__ u16 At[64][40];   // +8 pad
  __shared__ u16 Bq[64][40];
  __shared__ u16 Bv[64][40];
  __shared__ float ttile[64][76];  // epilogue transpose buffer (stride 76 ≡ 12 mod 32)

  const f32x4 fz = {0.f, 0.f, 0.f, 0.f};
  f32x4 accq[2][2], accv[2][2];
  #pragma unroll
  for (int i = 0; i < 2; i++)
    #pragma unroll
    for (int j = 0; j < 2; j++) { accq[i][j] = fz; accv[i][j] = fz; }

  const int srow = tid >> 2;
  const int soff = (tid & 3) * 8;
  const u16* ax = xt  + ((size_t)b * D_ + d0 + srow) * N_ + soff;
  const u16* bq = wqk + (size_t)(j0 + srow) * N_ + soff;
  const u16* bv = wv  + (size_t)(j0 + srow) * N_ + soff;

  for (int k0 = 0; k0 < N_; k0 += 32) {
    __syncthreads();
    *(u32x4*)&At[srow][soff] = *(const u32x4*)(ax + k0);
    *(u32x4*)&Bq[srow][soff] = *(const u32x4*)(bq + k0);
    *(u32x4*)&Bv[srow][soff] = *(const u32x4*)(bv + k0);
    __syncthreads();
    bf16x8 Af[2], Bqf[2], Bvf[2];
    #pragma unroll
    for (int mi = 0; mi < 2; mi++)
      Af[mi] = *(const bf16x8*)&At[wm * 32 + mi * 16 + l15][quad * 8];
    #pragma unroll
    for (int ni = 0; ni < 2; ni++) {
      Bqf[ni] = *(const bf16x8*)&Bq[wn * 32 + ni * 16 + l15][quad * 8];
      Bvf[ni] = *(const bf16x8*)&Bv[wn * 32 + ni * 16 + l15][quad * 8];
    }
    #pragma unroll
    for (int mi = 0; mi < 2; mi++)
      #pragma unroll
      for (int ni = 0; ni < 2; ni++) {
        accq[mi][ni] = __builtin_amdgcn_mfma_f32_16x16x32_bf16(Af[mi], Bqf[ni], accq[mi][ni], 0, 0, 0);
        accv[mi][ni] = __builtin_amdgcn_mfma_f32_16x16x32_bf16(Af[mi], Bvf[ni], accv[mi][ni], 0, 0, 0);
      }
  }

  const size_t bh = (size_t)(b * H_ + h);

  // q2 partial sums (C layout: col=lane&15, row=quad*4+r)
  #pragma unroll
  for (int mi = 0; mi < 2; mi++)
    #pragma unroll
    for (int r = 0; r < 4; r++) {
      const int d = d0 + wm * 32 + mi * 16 + quad * 4 + r;
      float ssq = 0.f;
      #pragma unroll
      for (int ni = 0; ni < 2; ni++) {
        float val = accq[mi][ni][r];
        ssq += val * val;
      }
      ssq += __shfl_xor(ssq, 1, 64);
      ssq += __shfl_xor(ssq, 2, 64);
      ssq += __shfl_xor(ssq, 4, 64);
      ssq += __shfl_xor(ssq, 8, 64);
      if (l15 == 0) atomicAdd(&q2[bh * D_ + d], ssq);
    }

  // ---- qk epilogue: LDS transpose -> fragment-tiled store ----
  // ttile[d_local][jn_local]
  #pragma unroll
  for (int mi = 0; mi < 2; mi++)
    #pragma unroll
    for (int ni = 0; ni < 2; ni++)
      #pragma unroll
      for (int r = 0; r < 4; r++)
        ttile[wm * 32 + mi * 16 + quad * 4 + r][wn * 32 + ni * 16 + l15] = accq[mi][ni][r];
  __syncthreads();
  u16* qtbase = qkb + bh * (size_t)(D_ * HN) + (size_t)dtile * 12288 + (size_t)(jn0 >> 3) * 512;
  #pragma unroll
  for (int i = 0; i < 2; i++) {
    const int p = tid + i * 256;
    const int d = p & 63, g8 = p >> 6;     // g8 in [0,8): jn8 group within this 64-col block
    u16 tmp[8];
    #pragma unroll
    for (int j = 0; j < 8; j++) tmp[j] = f2bf(ttile[d][g8 * 8 + j]);
    *(u32x4*)(qtbase + (size_t)(g8 * 64 + d) * 8) = *(u32x4*)tmp;
  }
  __syncthreads();

  // ---- v epilogue: ttile[jn_local][d_local] -> fragment-tiled store ----
  #pragma unroll
  for (int mi = 0; mi < 2; mi++)
    #pragma unroll
    for (int ni = 0; ni < 2; ni++)
      *(f32x4*)&ttile[wn * 32 + ni * 16 + l15][wm * 32 + mi * 16 + quad * 4] = accv[mi][ni];
  __syncthreads();
  u16* vtbase = vtb + bh * (size_t)(D_ * HN) + (size_t)dtile * 12288;
  #pragma unroll
  for (int i = 0; i < 2; i++) {
    const int p = tid + i * 256;
    const int jn = p & 63, d8 = p >> 6;    // d8 = e8 group
    u16 tmp[8];
    #pragma unroll
    for (int j = 0; j < 8; j++) tmp[j] = f2bf(ttile[jn][d8 * 8 + j]);
    *(u32x4*)(vtbase + (size_t)(d8 * 192 + jn0 + jn) * 8) = *(u32x4*)tmp;
  }
}

// ---------------------------------------------------------------------------
// Kernel 2: fused attention, analytic-max softmax.
//   p(d,e) = exp(2*QK - q2[e] - q2[d])  (row max = diagonal, known a priori)
//   O = (P @ V) / rowsum ; written merged-head to wbuf (B,D,N) bf16.
// Block: one (b,h), 128 Q-rows (2 groups of 64); wave = 16 rows per group.
// K/V tiles DMA'd to LDS via global_load_lds from fragment-tiled layouts.
// XCD swizzle: all 16 blocks of one bh co-resident on one XCD.
// ---------------------------------------------------------------------------
__global__ __launch_bounds__(256, 2) void attn_kernel(const u16* __restrict__ qkb,
                                                      const u16* __restrict__ vtb,
                                                      const float* __restrict__ q2,
                                                      u16* __restrict__ wbuf) {
  const int bid = blockIdx.x;
  const int xcd = bid & 7;
  const int grp = bid >> 3;
  const int bh  = xcd + 8 * (grp >> 4);
  const int dt2 = grp & 15;               // 128-row tile index
  const int b = bh >> 2, h = bh & 3;
  const int tid  = threadIdx.x;
  const int wave = tid >> 6, lane = tid & 63;
  const int l15  = lane & 15, quad = lane >> 4;

  __shared__ u16 Klds[12288];   // [jn8 24][e 64][8]  = 24 KB, DMA-linear
  __shared__ u16 Vlds[12288];   // [e8 8][jn 192][8]  = 24 KB, DMA-linear
  __shared__ u16 Pl[4][16][72]; // per-wave P round-trip (C->A layout), padded

  const u16* kbase = qkb + (size_t)bh * (D_ * HN);
  const u16* vbase = vtb + (size_t)bh * (D_ * HN);
  const float* q2g = q2 + (size_t)bh * D_;

  // Q fragments (A layout) for the two 64-row groups
  bf16x8 Qf[2][6];
  #pragma unroll
  for (int gg = 0; gg < 2; gg++) {
    const int dtile = dt2 * 2 + gg;
    const u16* qsrc = kbase + (size_t)dtile * 12288 + (size_t)quad * 512 + (size_t)(wave * 16 + l15) * 8;
    #pragma unroll
    for (int f = 0; f < 6; f++)
      Qf[gg][f] = *(const bf16x8*)(qsrc + f * 2048);
  }
  // row biases q2[d] (constant over the whole loop — analytic max)
  float cd[2][4];
  #pragma unroll
  for (int gg = 0; gg < 2; gg++)
    #pragma unroll
    for (int r = 0; r < 4; r++)
      cd[gg][r] = q2g[dt2 * 128 + gg * 64 + wave * 16 + quad * 4 + r];

  const f32x4 fz = {0.f, 0.f, 0.f, 0.f};
  f32x4 O[2][12];
  #pragma unroll
  for (int gg = 0; gg < 2; gg++)
    #pragma unroll
    for (int c = 0; c < 12; c++) O[gg][c] = fz;
  float rs[2][4];
  #pragma unroll
  for (int gg = 0; gg < 2; gg++)
    #pragma unroll
    for (int r = 0; r < 4; r++) rs[gg][r] = 0.f;

  for (int e0 = 0; e0 < D_; e0 += 64) {
    const int t = e0 >> 6;
    __syncthreads();   // all waves done reading previous K/V tiles
    {
      const u16* kt = kbase + (size_t)t * 12288 + wave * 3072 + lane * 8;
      const u16* vt = vbase + (size_t)t * 12288 + wave * 3072 + lane * 8;
      #pragma unroll
      for (int i = 0; i < 6; i++) {
        gld16(kt + i * 512, &Klds[wave * 3072 + i * 512]);
        gld16(vt + i * 512, &Vlds[wave * 3072 + i * 512]);
      }
    }
    // column biases for this tile (L2-resident)
    float ce[4];
    #pragma unroll
    for (int ni = 0; ni < 4; ni++) ce[ni] = q2g[e0 + ni * 16 + l15];
    __syncthreads();   // implied vmcnt(0) drain: DMA complete for all waves

    #pragma unroll
    for (int gg = 0; gg < 2; gg++) {
      // S = Q K^T : 16 rows x 64 cols per wave
      f32x4 S[4];
      #pragma unroll
      for (int ni = 0; ni < 4; ni++) {
        f32x4 acc = fz;
        #pragma unroll
        for (int f = 0; f < 6; f++) {
          bf16x8 Kf = *(const bf16x8*)&Klds[(f * 4 + quad) * 512 + (ni * 16 + l15) * 8];
          acc = __builtin_amdgcn_mfma_f32_16x16x32_bf16(Qf[gg][f], Kf, acc, 0, 0, 0);
        }
        S[ni] = acc;
      }
      // p = exp(2S - q2e - q2d); sum accumulated per-lane (reduced once at end)
      #pragma unroll
      for (int ni = 0; ni < 4; ni++)
        #pragma unroll
        for (int r = 0; r < 4; r++) {
          float p = __expf(__builtin_fmaf(S[ni][r], 2.f, -(ce[ni] + cd[gg][r])));
          S[ni][r] = p;
          rs[gg][r] += p;
        }
      // P: C layout -> LDS -> A layout (wave-private, no barrier)
      #pragma unroll
      for (int ni = 0; ni < 4; ni++)
        #pragma unroll
        for (int r = 0; r < 4; r++)
          Pl[wave][quad * 4 + r][ni * 16 + l15] = f2bf(S[ni][r]);
      #pragma unroll
      for (int kk = 0; kk < 2; kk++) {
        bf16x8 Pf = *(const bf16x8*)&Pl[wave][l15][kk * 32 + quad * 8];
        #pragma unroll
        for (int c = 0; c < 12; c++) {
          bf16x8 Vf = *(const bf16x8*)&Vlds[((kk * 4 + quad) * 192 + c * 16 + l15) * 8];
          O[gg][c] = __builtin_amdgcn_mfma_f32_16x16x32_bf16(Pf, Vf, O[gg][c], 0, 0, 0);
        }
      }
    }
  }

  // reduce row sums across the 16 column-lanes, once
  #pragma unroll
  for (int gg = 0; gg < 2; gg++)
    #pragma unroll
    for (int r = 0; r < 4; r++) {
      float s = rs[gg][r];
      s += __shfl_xor(s, 1, 64);
      s += __shfl_xor(s, 2, 64);
      s += __shfl_xor(s, 4, 64);
      s += __shfl_xor(s, 8, 64);
      rs[gg][r] = s;
    }

  // normalize + merged-head store: wbuf[b, d, h*192 + col] bf16
  #pragma unroll
  for (int gg = 0; gg < 2; gg++)
    #pragma unroll
    for (int r = 0; r < 4; r++) {
      const float inv = 1.f / rs[gg][r];
      const int d = dt2 * 128 + gg * 64 + wave * 16 + quad * 4 + r;
      u16* wrow = wbuf + ((size_t)b * D_ + d) * N_ + h * HN;
      #pragma unroll
      for (int c = 0; c < 12; c++)
        wrow[c * 16 + l15] = f2bf(O[gg][c][r] * inv);
    }
}

// ---------------------------------------------------------------------------
// Kernel 3: out GEMM + transpose.  out[b,i,d] = sum_j w[b,d,j]*Wout[i,j] (fp32)
// ---------------------------------------------------------------------------
__global__ __launch_bounds__(256) void out_gemm(const u16* __restrict__ wbuf,
                                                const u16* __restrict__ wout,
                                                float* __restrict__ outp) {
  const int b  = blockIdx.z;
  const int d0 = blockIdx.x * 64;
  const int i0 = blockIdx.y * 64;
  const int tid  = threadIdx.x;
  const int wave = tid >> 6, lane = tid & 63;
  const int l15  = lane & 15, quad = lane >> 4;
  const int wm = wave >> 1, wn = wave & 1;

  __shared__ u16 At[64][40];
  __shared__ u16 Bt[64][40];
  __shared__ float otile[64][68];

  const f32x4 fz = {0.f, 0.f, 0.f, 0.f};
  f32x4 acc[2][2];
  #pragma unroll
  for (int i = 0; i < 2; i++)
    #pragma unroll
    for (int j = 0; j < 2; j++) acc[i][j] = fz;

  const int srow = tid >> 2;
  const int soff = (tid & 3) * 8;
  const u16* ax = wbuf + ((size_t)b * D_ + d0 + srow) * N_ + soff;
  const u16* bw = wout + (size_t)(i0 + srow) * N_ + soff;

  for (int k0 = 0; k0 < N_; k0 += 32) {
    __syncthreads();
    *(u32x4*)&At[srow][soff] = *(const u32x4*)(ax + k0);
    *(u32x4*)&Bt[srow][soff] = *(const u32x4*)(bw + k0);
    __syncthreads();
    bf16x8 Af[2], Bf[2];
    #pragma unroll
    for (int mi = 0; mi < 2; mi++)
      Af[mi] = *(const bf16x8*)&At[wm * 32 + mi * 16 + l15][quad * 8];
    #pragma unroll
    for (int ni = 0; ni < 2; ni++)
      Bf[ni] = *(const bf16x8*)&Bt[wn * 32 + ni * 16 + l15][quad * 8];
    #pragma unroll
    for (int mi = 0; mi < 2; mi++)
      #pragma unroll
      for (int ni = 0; ni < 2; ni++)
        acc[mi][ni] = __builtin_amdgcn_mfma_f32_16x16x32_bf16(Af[mi], Bf[ni], acc[mi][ni], 0, 0, 0);
  }

  #pragma unroll
  for (int mi = 0; mi < 2; mi++)
    #pragma unroll
    for (int ni = 0; ni < 2; ni++)
      #pragma unroll
      for (int r = 0; r < 4; r++)
        otile[wn * 32 + ni * 16 + l15][wm * 32 + mi * 16 + quad * 4 + r] = acc[mi][ni][r];
  __syncthreads();
  const int il = tid >> 2;
  const int ch = (tid & 3) * 16;
  float* orow = outp + ((size_t)b * N_ + i0 + il) * D_ + d0 + ch;
  #pragma unroll
  for (int i = 0; i < 16; i += 4)
    *(f32x4*)(orow + i) = *(const f32x4*)&otile[il][ch + i];
}

// ---------------------------------------------------------------------------
extern "C" void kernel_launch(void* const* d_in, const int* in_sizes, int n_in,
                              void* d_out, int out_size, void* d_ws, size_t ws_size,
                              hipStream_t stream) {
  (void)in_sizes; (void)n_in; (void)out_size; (void)ws_size;
  const float* x    = (const float*)d_in[0];
  const float* Wqk  = (const float*)d_in[1];
  const float* Wv   = (const float*)d_in[2];
  const float* Wout = (const float*)d_in[3];
  float* outp = (float*)d_out;

  // Workspace layout (~79 MB total; all offsets 16B-aligned)
  char* ws = (char*)d_ws;
  size_t off = 0;
  u16* xt   = (u16*)(ws + off); off += (size_t)B_ * D_ * N_ * 2;        // 25.2 MB
  u16* qkb  = (u16*)(ws + off); off += (size_t)B_ * H_ * D_ * HN * 2;   // 25.2 MB
  u16* vtb  = (u16*)(ws + off); off += (size_t)B_ * H_ * HN * D_ * 2;   // 25.2 MB
  float* q2 = (float*)(ws + off); off += (size_t)B_ * H_ * D_ * 4;      // 256 KB
  u16* wqk_bf  = (u16*)(ws + off); off += (size_t)N_ * N_ * 2;
  u16* wv_bf   = (u16*)(ws + off); off += (size_t)N_ * N_ * 2;
  u16* wout_bf = (u16*)(ws + off); off += (size_t)N_ * N_ * 2;
  u16* wbuf = xt;   // xt dead after qkv_gemm; reuse for attention output

  transpose_x<<<dim3(D_ / 64, N_ / 64, B_), 256, 0, stream>>>(x, xt);
  cvt_w<<<dim3((N_ * N_) / (256 * 4), 3), 256, 0, stream>>>(Wqk, Wv, Wout, wqk_bf, wv_bf, wout_bf);
  zero_q2<<<dim3((B_ * H_ * D_) / 256), 256, 0, stream>>>(q2);
  qkv_gemm<<<dim3(D_ / 64, N_ / 64, B_), 256, 0, stream>>>(xt, wqk_bf, wv_bf, qkb, vtb, q2);
  attn_kernel<<<dim3((D_ / 128) * B_ * H_), 256, 0, stream>>>(qkb, vtb, q2, wbuf);
  out_gemm<<<dim3(D_ / 64, N_ / 64, B_), 256, 0, stream>>>(wbuf, wout_bf, outp);
}